// Round 1
// baseline (205.292 us; speedup 1.0000x reference)
//
#include <hip/hip_runtime.h>
#include <hip/hip_bf16.h>
#include <math.h>
#include <float.h>

// Problem constants
#define BSZ 16
#define SEQ 4096
#define HID 768
#define H4  192      // HID/4
#define NM  128      // mentions per batch
#define NSPAN 256    // 2*NM endpoint slots per batch
#define ENT 256
#define NTOT 2048    // BSZ*NM
#define SC  64       // sequence chunk size
#define NCH 64       // SEQ/SC

// ---------------------------------------------------------------------------
// Kernel 1: chunked scan over sequence_output.
// Grid: BSZ*NCH blocks, 192 threads (one float4 column of HID each).
// Emits within-chunk cumsum at every span endpoint that falls in this chunk
// (W[b][j][h], j = m*2+k slot), and the chunk total P[b][c][h].
// ---------------------------------------------------------------------------
__global__ __launch_bounds__(192) void span_scan_kernel(
    const float* __restrict__ seq, const int* __restrict__ spans,
    float* __restrict__ W, float* __restrict__ P) {
  int b = blockIdx.x / NCH;
  int c = blockIdx.x % NCH;
  int t = threadIdx.x;  // 0..191

  __shared__ int head[SC + 1];
  __shared__ int nxt[NSPAN];
  for (int i = t; i < SC + 1; i += 192) head[i] = -1;
  __syncthreads();
  for (int j = t; j < NSPAN; j += 192) {
    int e = spans[b * NSPAN + j];            // endpoint in [0, SEQ]
    int ch = e >> 6; if (ch > NCH - 1) ch = NCH - 1;
    if (ch == c) {
      int off = e - c * SC;                  // [0, SC]
      nxt[j] = atomicExch(&head[off], j);
    }
  }
  __syncthreads();

  const float4* seq4 =
      reinterpret_cast<const float4*>(seq) + (size_t)(b * SEQ + c * SC) * H4 + t;
  float4* W4 = reinterpret_cast<float4*>(W);
  float4 acc = make_float4(0.f, 0.f, 0.f, 0.f);
  for (int s = 0; s < SC; ++s) {
    // emit cumsum-so-far for endpoints == c*SC + s (exclusive of row s)
    for (int p = head[s]; p != -1; p = nxt[p]) {
      W4[(size_t)(b * NSPAN + p) * H4 + t] = acc;
    }
    float4 v = seq4[(size_t)s * H4];
    acc.x += v.x; acc.y += v.y; acc.z += v.z; acc.w += v.w;
  }
  for (int p = head[SC]; p != -1; p = nxt[p]) {
    W4[(size_t)(b * NSPAN + p) * H4 + t] = acc;
  }
  reinterpret_cast<float4*>(P)[(size_t)(b * NCH + c) * H4 + t] = acc;
}

// ---------------------------------------------------------------------------
// Kernel 2: in-place exclusive prefix over the NCH chunk sums per (b, h4).
// ---------------------------------------------------------------------------
__global__ void chunk_prefix_kernel(float* __restrict__ P) {
  int idx = blockIdx.x * blockDim.x + threadIdx.x;
  if (idx >= BSZ * H4) return;
  int b = idx / H4, h = idx % H4;
  float4* P4 = reinterpret_cast<float4*>(P);
  float4 run = make_float4(0.f, 0.f, 0.f, 0.f);
  for (int c = 0; c < NCH; ++c) {
    size_t o = (size_t)(b * NCH + c) * H4 + h;
    float4 v = P4[o];
    P4[o] = run;
    run.x += v.x; run.y += v.y; run.z += v.z; run.w += v.w;
  }
}

// ---------------------------------------------------------------------------
// Kernel 3: mention vectors = (cumsum[e1]-cumsum[e0]) / len, 0 when len==0.
// ---------------------------------------------------------------------------
__global__ void mention_vec_kernel(const float* __restrict__ W,
                                   const float* __restrict__ P,
                                   const int* __restrict__ spans,
                                   float* __restrict__ MV) {
  int idx = blockIdx.x * blockDim.x + threadIdx.x;
  if (idx >= NTOT * H4) return;
  int bm = idx / H4, h = idx % H4;
  int b = bm >> 7, m = bm & (NM - 1);
  int e0 = spans[bm * 2], e1 = spans[bm * 2 + 1];
  int c0 = e0 >> 6; if (c0 > NCH - 1) c0 = NCH - 1;
  int c1 = e1 >> 6; if (c1 > NCH - 1) c1 = NCH - 1;
  const float4* W4 = reinterpret_cast<const float4*>(W);
  const float4* P4 = reinterpret_cast<const float4*>(P);
  float4 p0 = P4[(size_t)(b * NCH + c0) * H4 + h];
  float4 p1 = P4[(size_t)(b * NCH + c1) * H4 + h];
  float4 w0 = W4[(size_t)(b * NSPAN + 2 * m) * H4 + h];
  float4 w1 = W4[(size_t)(b * NSPAN + 2 * m + 1) * H4 + h];
  float sx = (p1.x + w1.x) - (p0.x + w0.x);
  float sy = (p1.y + w1.y) - (p0.y + w0.y);
  float sz = (p1.z + w1.z) - (p0.z + w0.z);
  float sw = (p1.w + w1.w) - (p0.w + w0.w);
  int len = e1 - e0;
  float4 r;
  if (len > 0) {
    float fl = (float)len;
    r = make_float4(sx / fl, sy / fl, sz / fl, sw / fl);
  } else {
    r = make_float4(0.f, 0.f, 0.f, 0.f);  // 0/0 -> nan_to_num -> 0
  }
  reinterpret_cast<float4*>(MV)[(size_t)bm * H4 + h] = r;
}

// ---------------------------------------------------------------------------
// Kernel 4: transpose linear_w [ENT][HID] -> WT [HID][ENT] for coalesced GEMV.
// ---------------------------------------------------------------------------
__global__ void wt_transpose_kernel(const float* __restrict__ lw,
                                    float* __restrict__ WT) {
  int idx = blockIdx.x * blockDim.x + threadIdx.x;
  if (idx >= ENT * HID) return;
  int k = idx / ENT, e = idx % ENT;
  WT[idx] = lw[e * HID + k];
}

// ---------------------------------------------------------------------------
// Kernel 5: entity vectors EV[i][e] = dot(MV[i], linear_w[e]) + bias[e].
// Block: 256 threads (one output column each), EVROWS rows per block.
// ---------------------------------------------------------------------------
#define EVROWS 4
__global__ __launch_bounds__(256) void ev_gemm_kernel(
    const float* __restrict__ MV, const float* __restrict__ WT,
    const float* __restrict__ bias, float* __restrict__ EVa,
    float* __restrict__ out) {
  int t = threadIdx.x;
  int i0 = blockIdx.x * EVROWS;
  __shared__ float mv[EVROWS][HID];
  float4* mv4 = reinterpret_cast<float4*>(&mv[0][0]);
  const float4* src = reinterpret_cast<const float4*>(MV) + (size_t)i0 * H4;
  for (int q = t; q < EVROWS * H4; q += 256) mv4[q] = src[q];
  __syncthreads();
  float acc[EVROWS] = {0.f, 0.f, 0.f, 0.f};
  for (int k = 0; k < HID; ++k) {
    float w = WT[k * ENT + t];
#pragma unroll
    for (int r = 0; r < EVROWS; ++r) acc[r] += mv[r][k] * w;
  }
  float bv = bias[t];
#pragma unroll
  for (int r = 0; r < EVROWS; ++r) {
    float v = acc[r] + bv;
    EVa[(size_t)(i0 + r) * ENT + t] = v;
    out[1 + (size_t)(i0 + r) * ENT + t] = v;
  }
}

// ---------------------------------------------------------------------------
// Kernel 6: gather label embeddings transposed: LET[k][j] = table[lab[j]][k].
// One wave per row j; coalesced float4 reads of the table row.
// ---------------------------------------------------------------------------
__global__ void gather_le_kernel(const float* __restrict__ table,
                                 const int* __restrict__ labels,
                                 float* __restrict__ LET) {
  int j = blockIdx.x;   // 0..NTOT-1
  int t = threadIdx.x;  // 0..63
  int lab = labels[(j >> 7) * 256 + (j & 127)];  // labels[b][0][m]
  const float4* row = reinterpret_cast<const float4*>(table + (size_t)lab * ENT);
  float4 v = row[t];
  int k = t * 4;
  LET[(size_t)(k + 0) * NTOT + j] = v.x;
  LET[(size_t)(k + 1) * NTOT + j] = v.y;
  LET[(size_t)(k + 2) * NTOT + j] = v.z;
  LET[(size_t)(k + 3) * NTOT + j] = v.w;
}

// ---------------------------------------------------------------------------
// Kernel 7: per-row contrastive loss. Block handles LROWS rows; each thread
// owns 8 logit columns; full row block stays in registers.
// ---------------------------------------------------------------------------
#define LROWS 8
__global__ __launch_bounds__(256) void loss_rows_kernel(
    const float* __restrict__ EVa, const float* __restrict__ LET,
    float* __restrict__ perrow) {
  int t = threadIdx.x;
  int i0 = blockIdx.x * LROWS;
  __shared__ float evs[LROWS][ENT];
  __shared__ float red[LROWS][4];
  __shared__ float diag[LROWS];
  float4* evs4 = reinterpret_cast<float4*>(&evs[0][0]);
  const float4* src = reinterpret_cast<const float4*>(EVa + (size_t)i0 * ENT);
  for (int q = t; q < LROWS * ENT / 4; q += 256) evs4[q] = src[q];
  __syncthreads();

  float acc[LROWS][8];
#pragma unroll
  for (int r = 0; r < LROWS; ++r)
#pragma unroll
    for (int c = 0; c < 8; ++c) acc[r][c] = 0.f;

  for (int k = 0; k < ENT; ++k) {
    float evk[LROWS];
#pragma unroll
    for (int r = 0; r < LROWS; ++r) evk[r] = evs[r][k];  // LDS broadcast
#pragma unroll
    for (int c = 0; c < 8; ++c) {
      float lv = LET[(size_t)k * NTOT + c * 256 + t];
#pragma unroll
      for (int r = 0; r < LROWS; ++r) acc[r][c] += evk[r] * lv;
    }
  }

  // diagonal logits
#pragma unroll
  for (int r = 0; r < LROWS; ++r) {
    int i = i0 + r;
    if (t == (i & 255)) diag[r] = acc[r][i >> 8];
  }

  int lane = t & 63, wid = t >> 6;
  // row maxes
#pragma unroll
  for (int r = 0; r < LROWS; ++r) {
    float m = acc[r][0];
#pragma unroll
    for (int c = 1; c < 8; ++c) m = fmaxf(m, acc[r][c]);
    for (int o = 32; o >= 1; o >>= 1) m = fmaxf(m, __shfl_xor(m, o));
    if (lane == 0) red[r][wid] = m;
  }
  __syncthreads();
  float rowmax[LROWS];
#pragma unroll
  for (int r = 0; r < LROWS; ++r)
    rowmax[r] = fmaxf(fmaxf(red[r][0], red[r][1]), fmaxf(red[r][2], red[r][3]));
  __syncthreads();
  // row exp-sums
#pragma unroll
  for (int r = 0; r < LROWS; ++r) {
    float s = 0.f;
#pragma unroll
    for (int c = 0; c < 8; ++c) s += expf(acc[r][c] - rowmax[r]);
    for (int o = 32; o >= 1; o >>= 1) s += __shfl_xor(s, o);
    if (lane == 0) red[r][wid] = s;
  }
  __syncthreads();
  if (t < LROWS) {
    int r = t;
    float s = red[r][0] + red[r][1] + red[r][2] + red[r][3];
    perrow[i0 + r] = (logf(s) + rowmax[r]) - diag[r];
  }
}

// ---------------------------------------------------------------------------
// Kernel 8: deterministic final reduce -> loss scalar.
// ---------------------------------------------------------------------------
__global__ void finalize_kernel(const float* __restrict__ perrow,
                                const int* __restrict__ labels,
                                float* __restrict__ out) {
  int t = threadIdx.x;  // 256
  float s = 0.f, cnt = 0.f;
  for (int i = t; i < NTOT; i += 256) {
    int status = labels[(i >> 7) * 256 + 128 + (i & 127)];  // labels[b][1][m]
    if (status >= 0) { s += perrow[i]; cnt += 1.f; }
  }
  __shared__ float rs[256], rc[256];
  rs[t] = s; rc[t] = cnt;
  __syncthreads();
  for (int o = 128; o > 0; o >>= 1) {
    if (t < o) { rs[t] += rs[t + o]; rc[t] += rc[t + o]; }
    __syncthreads();
  }
  if (t == 0) {
    float L = rc[0] > 0.f ? rs[0] / rc[0] : 0.f;
    if (isnan(L)) L = 0.f;
    if (isinf(L)) L = L > 0.f ? FLT_MAX : -FLT_MAX;
    out[0] = L;
  }
}

// ---------------------------------------------------------------------------
extern "C" void kernel_launch(void* const* d_in, const int* in_sizes, int n_in,
                              void* d_out, int out_size, void* d_ws,
                              size_t ws_size, hipStream_t stream) {
  const float* seq   = (const float*)d_in[0];  // [16,4096,768]
  const float* lw    = (const float*)d_in[1];  // [256,768]
  const float* lb    = (const float*)d_in[2];  // [256]
  const float* table = (const float*)d_in[3];  // [50000,256]
  const int* spans   = (const int*)d_in[4];    // [16,128,2]
  const int* labels  = (const int*)d_in[5];    // [16,2,128]
  float* out = (float*)d_out;                  // [1 + 16*128*256]
  float* ws = (float*)d_ws;

  // workspace layout (floats)
  float* W      = ws;                         // [16][256][768]  sampled in-chunk cumsums
  float* P      = W + (size_t)BSZ * NSPAN * HID;   // [16][64][768] chunk sums -> exclusive prefix
  float* MV     = P + (size_t)BSZ * NCH * HID;     // [2048][768]  mention vectors
  float* WT     = MV + (size_t)NTOT * HID;         // [768][256]   linear_w transposed
  float* EVa    = WT + (size_t)HID * ENT;          // [2048][256]  aligned entity vectors
  float* LET    = EVa + (size_t)NTOT * ENT;        // [256][2048]  label embs transposed
  float* perrow = LET + (size_t)ENT * NTOT;        // [2048]

  span_scan_kernel<<<BSZ * NCH, 192, 0, stream>>>(seq, spans, W, P);
  chunk_prefix_kernel<<<(BSZ * H4 + 255) / 256, 256, 0, stream>>>(P);
  mention_vec_kernel<<<(NTOT * H4 + 255) / 256, 256, 0, stream>>>(W, P, spans, MV);
  wt_transpose_kernel<<<(ENT * HID + 255) / 256, 256, 0, stream>>>(lw, WT);
  ev_gemm_kernel<<<NTOT / EVROWS, 256, 0, stream>>>(MV, WT, lb, EVa, out);
  gather_le_kernel<<<NTOT, 64, 0, stream>>>(table, labels, LET);
  loss_rows_kernel<<<NTOT / LROWS, 256, 0, stream>>>(EVa, LET, perrow);
  finalize_kernel<<<1, 256, 0, stream>>>(perrow, labels, out);
}

// Round 2
// 160.613 us; speedup vs baseline: 1.2782x; 1.2782x over previous
//
#include <hip/hip_runtime.h>
#include <hip/hip_bf16.h>
#include <math.h>
#include <float.h>

// Problem constants
#define BSZ 16
#define SEQ 4096
#define HID 768
#define H4  192      // HID/4
#define NM  128      // mentions per batch
#define NSPAN 256    // 2*NM endpoint slots per batch
#define ENT 256
#define NTOT 2048    // BSZ*NM
#define SC  64       // sequence chunk size
#define NCH 64       // SEQ/SC

// ---------------------------------------------------------------------------
// Kernel 1: chunked scan over sequence_output.
// Grid: BSZ*NCH blocks, 192 threads (one float4 column of HID each).
// Emits within-chunk cumsum at every span endpoint that falls in this chunk
// (W[b][j][h], j = m*2+k slot), and the chunk total P[b][c][h].
// ---------------------------------------------------------------------------
__global__ __launch_bounds__(192) void span_scan_kernel(
    const float* __restrict__ seq, const int* __restrict__ spans,
    float* __restrict__ W, float* __restrict__ P) {
  int b = blockIdx.x / NCH;
  int c = blockIdx.x % NCH;
  int t = threadIdx.x;  // 0..191

  __shared__ int head[SC + 1];
  __shared__ int nxt[NSPAN];
  for (int i = t; i < SC + 1; i += 192) head[i] = -1;
  __syncthreads();
  for (int j = t; j < NSPAN; j += 192) {
    int e = spans[b * NSPAN + j];            // endpoint in [0, SEQ]
    int ch = e >> 6; if (ch > NCH - 1) ch = NCH - 1;
    if (ch == c) {
      int off = e - c * SC;                  // [0, SC]
      nxt[j] = atomicExch(&head[off], j);
    }
  }
  __syncthreads();

  const float4* seq4 =
      reinterpret_cast<const float4*>(seq) + (size_t)(b * SEQ + c * SC) * H4 + t;
  float4* W4 = reinterpret_cast<float4*>(W);
  float4 acc = make_float4(0.f, 0.f, 0.f, 0.f);
  for (int s = 0; s < SC; ++s) {
    // emit cumsum-so-far for endpoints == c*SC + s (exclusive of row s)
    for (int p = head[s]; p != -1; p = nxt[p]) {
      W4[(size_t)(b * NSPAN + p) * H4 + t] = acc;
    }
    float4 v = seq4[(size_t)s * H4];
    acc.x += v.x; acc.y += v.y; acc.z += v.z; acc.w += v.w;
  }
  for (int p = head[SC]; p != -1; p = nxt[p]) {
    W4[(size_t)(b * NSPAN + p) * H4 + t] = acc;
  }
  reinterpret_cast<float4*>(P)[(size_t)(b * NCH + c) * H4 + t] = acc;
}

// ---------------------------------------------------------------------------
// Kernel 2: in-place exclusive prefix over the NCH chunk sums per (b, h4).
// ---------------------------------------------------------------------------
__global__ void chunk_prefix_kernel(float* __restrict__ P) {
  int idx = blockIdx.x * blockDim.x + threadIdx.x;
  if (idx >= BSZ * H4) return;
  int b = idx / H4, h = idx % H4;
  float4* P4 = reinterpret_cast<float4*>(P);
  float4 run = make_float4(0.f, 0.f, 0.f, 0.f);
  for (int c = 0; c < NCH; ++c) {
    size_t o = (size_t)(b * NCH + c) * H4 + h;
    float4 v = P4[o];
    P4[o] = run;
    run.x += v.x; run.y += v.y; run.z += v.z; run.w += v.w;
  }
}

// ---------------------------------------------------------------------------
// Kernel 3: mention vectors = (cumsum[e1]-cumsum[e0]) / len, 0 when len==0.
// ---------------------------------------------------------------------------
__global__ void mention_vec_kernel(const float* __restrict__ W,
                                   const float* __restrict__ P,
                                   const int* __restrict__ spans,
                                   float* __restrict__ MV) {
  int idx = blockIdx.x * blockDim.x + threadIdx.x;
  if (idx >= NTOT * H4) return;
  int bm = idx / H4, h = idx % H4;
  int b = bm >> 7, m = bm & (NM - 1);
  int e0 = spans[bm * 2], e1 = spans[bm * 2 + 1];
  int c0 = e0 >> 6; if (c0 > NCH - 1) c0 = NCH - 1;
  int c1 = e1 >> 6; if (c1 > NCH - 1) c1 = NCH - 1;
  const float4* W4 = reinterpret_cast<const float4*>(W);
  const float4* P4 = reinterpret_cast<const float4*>(P);
  float4 p0 = P4[(size_t)(b * NCH + c0) * H4 + h];
  float4 p1 = P4[(size_t)(b * NCH + c1) * H4 + h];
  float4 w0 = W4[(size_t)(b * NSPAN + 2 * m) * H4 + h];
  float4 w1 = W4[(size_t)(b * NSPAN + 2 * m + 1) * H4 + h];
  float sx = (p1.x + w1.x) - (p0.x + w0.x);
  float sy = (p1.y + w1.y) - (p0.y + w0.y);
  float sz = (p1.z + w1.z) - (p0.z + w0.z);
  float sw = (p1.w + w1.w) - (p0.w + w0.w);
  int len = e1 - e0;
  float4 r;
  if (len > 0) {
    float fl = (float)len;
    r = make_float4(sx / fl, sy / fl, sz / fl, sw / fl);
  } else {
    r = make_float4(0.f, 0.f, 0.f, 0.f);  // 0/0 -> nan_to_num -> 0
  }
  reinterpret_cast<float4*>(MV)[(size_t)bm * H4 + h] = r;
}

// ---------------------------------------------------------------------------
// Kernel 4: transpose linear_w [ENT][HID] -> WT [HID][ENT] for coalesced GEMV.
// ---------------------------------------------------------------------------
__global__ void wt_transpose_kernel(const float* __restrict__ lw,
                                    float* __restrict__ WT) {
  int idx = blockIdx.x * blockDim.x + threadIdx.x;
  if (idx >= ENT * HID) return;
  int k = idx / ENT, e = idx % ENT;
  WT[idx] = lw[e * HID + k];
}

// ---------------------------------------------------------------------------
// Kernel 5: entity vectors EV[i][e] = dot(MV[i], linear_w[e]) + bias[e].
// Block: 256 threads (one output column each), EVROWS rows per block.
// ---------------------------------------------------------------------------
#define EVROWS 4
__global__ __launch_bounds__(256) void ev_gemm_kernel(
    const float* __restrict__ MV, const float* __restrict__ WT,
    const float* __restrict__ bias, float* __restrict__ EVa,
    float* __restrict__ out) {
  int t = threadIdx.x;
  int i0 = blockIdx.x * EVROWS;
  __shared__ float mv[EVROWS][HID];
  float4* mv4 = reinterpret_cast<float4*>(&mv[0][0]);
  const float4* src = reinterpret_cast<const float4*>(MV) + (size_t)i0 * H4;
  for (int q = t; q < EVROWS * H4; q += 256) mv4[q] = src[q];
  __syncthreads();
  float acc[EVROWS] = {0.f, 0.f, 0.f, 0.f};
  for (int k = 0; k < HID; ++k) {
    float w = WT[k * ENT + t];
#pragma unroll
    for (int r = 0; r < EVROWS; ++r) acc[r] += mv[r][k] * w;
  }
  float bv = bias[t];
#pragma unroll
  for (int r = 0; r < EVROWS; ++r) {
    float v = acc[r] + bv;
    EVa[(size_t)(i0 + r) * ENT + t] = v;
    out[1 + (size_t)(i0 + r) * ENT + t] = v;
  }
}

// ---------------------------------------------------------------------------
// Kernel 6: gather label embeddings transposed: LET[k][j] = table[lab[j]][k].
// One wave per row j; coalesced float4 reads of the table row.
// ---------------------------------------------------------------------------
__global__ void gather_le_kernel(const float* __restrict__ table,
                                 const int* __restrict__ labels,
                                 float* __restrict__ LET) {
  int j = blockIdx.x;   // 0..NTOT-1
  int t = threadIdx.x;  // 0..63
  int lab = labels[(j >> 7) * 256 + (j & 127)];  // labels[b][0][m]
  const float4* row = reinterpret_cast<const float4*>(table + (size_t)lab * ENT);
  float4 v = row[t];
  int k = t * 4;
  LET[(size_t)(k + 0) * NTOT + j] = v.x;
  LET[(size_t)(k + 1) * NTOT + j] = v.y;
  LET[(size_t)(k + 2) * NTOT + j] = v.z;
  LET[(size_t)(k + 3) * NTOT + j] = v.w;
}

// ---------------------------------------------------------------------------
// Kernel 7: per-row contrastive loss. Block handles LROWS rows; each thread
// owns 8 logit columns; full row block stays in REGISTERS (all acc indices
// are compile-time constants — rule #20: no runtime indexing).
// ---------------------------------------------------------------------------
#define LROWS 8
__global__ __launch_bounds__(256) void loss_rows_kernel(
    const float* __restrict__ EVa, const float* __restrict__ LET,
    float* __restrict__ perrow) {
  int t = threadIdx.x;
  int i0 = blockIdx.x * LROWS;
  __shared__ float evs[LROWS][ENT];
  __shared__ float red[LROWS][4];
  __shared__ float diag[LROWS];
  float4* evs4 = reinterpret_cast<float4*>(&evs[0][0]);
  const float4* src = reinterpret_cast<const float4*>(EVa + (size_t)i0 * ENT);
  for (int q = t; q < LROWS * ENT / 4; q += 256) evs4[q] = src[q];
  __syncthreads();

  float acc[LROWS][8];
#pragma unroll
  for (int r = 0; r < LROWS; ++r)
#pragma unroll
    for (int c = 0; c < 8; ++c) acc[r][c] = 0.f;

  for (int k = 0; k < ENT; ++k) {
    float evk[LROWS];
#pragma unroll
    for (int r = 0; r < LROWS; ++r) evk[r] = evs[r][k];  // LDS broadcast
#pragma unroll
    for (int c = 0; c < 8; ++c) {
      float lv = LET[(size_t)k * NTOT + c * 256 + t];
#pragma unroll
      for (int r = 0; r < LROWS; ++r) acc[r][c] += evk[r] * lv;
    }
  }

  // diagonal logits — extract with COMPILE-TIME indices only (compare c
  // against the runtime diag column; acc[r][c] index stays constant).
#pragma unroll
  for (int r = 0; r < LROWS; ++r) {
    int i = i0 + r;
    int cdiag = i >> 8;    // which of this thread's 8 columns holds the diag
    int tdiag = i & 255;   // which thread owns it
#pragma unroll
    for (int c = 0; c < 8; ++c) {
      if (c == cdiag && t == tdiag) diag[r] = acc[r][c];
    }
  }

  int lane = t & 63, wid = t >> 6;
  // row maxes
#pragma unroll
  for (int r = 0; r < LROWS; ++r) {
    float m = acc[r][0];
#pragma unroll
    for (int c = 1; c < 8; ++c) m = fmaxf(m, acc[r][c]);
    for (int o = 32; o >= 1; o >>= 1) m = fmaxf(m, __shfl_xor(m, o));
    if (lane == 0) red[r][wid] = m;
  }
  __syncthreads();
  float rowmax[LROWS];
#pragma unroll
  for (int r = 0; r < LROWS; ++r)
    rowmax[r] = fmaxf(fmaxf(red[r][0], red[r][1]), fmaxf(red[r][2], red[r][3]));
  __syncthreads();
  // row exp-sums
#pragma unroll
  for (int r = 0; r < LROWS; ++r) {
    float s = 0.f;
#pragma unroll
    for (int c = 0; c < 8; ++c) s += expf(acc[r][c] - rowmax[r]);
    for (int o = 32; o >= 1; o >>= 1) s += __shfl_xor(s, o);
    if (lane == 0) red[r][wid] = s;
  }
  __syncthreads();
  if (t < LROWS) {
    int r = t;
    float s = red[r][0] + red[r][1] + red[r][2] + red[r][3];
    perrow[i0 + r] = (logf(s) + rowmax[r]) - diag[r];
  }
}

// ---------------------------------------------------------------------------
// Kernel 8: deterministic final reduce -> loss scalar.
// ---------------------------------------------------------------------------
__global__ void finalize_kernel(const float* __restrict__ perrow,
                                const int* __restrict__ labels,
                                float* __restrict__ out) {
  int t = threadIdx.x;  // 256
  float s = 0.f, cnt = 0.f;
  for (int i = t; i < NTOT; i += 256) {
    int status = labels[(i >> 7) * 256 + 128 + (i & 127)];  // labels[b][1][m]
    if (status >= 0) { s += perrow[i]; cnt += 1.f; }
  }
  __shared__ float rs[256], rc[256];
  rs[t] = s; rc[t] = cnt;
  __syncthreads();
  for (int o = 128; o > 0; o >>= 1) {
    if (t < o) { rs[t] += rs[t + o]; rc[t] += rc[t + o]; }
    __syncthreads();
  }
  if (t == 0) {
    float L = rc[0] > 0.f ? rs[0] / rc[0] : 0.f;
    if (isnan(L)) L = 0.f;
    if (isinf(L)) L = L > 0.f ? FLT_MAX : -FLT_MAX;
    out[0] = L;
  }
}

// ---------------------------------------------------------------------------
extern "C" void kernel_launch(void* const* d_in, const int* in_sizes, int n_in,
                              void* d_out, int out_size, void* d_ws,
                              size_t ws_size, hipStream_t stream) {
  const float* seq   = (const float*)d_in[0];  // [16,4096,768]
  const float* lw    = (const float*)d_in[1];  // [256,768]
  const float* lb    = (const float*)d_in[2];  // [256]
  const float* table = (const float*)d_in[3];  // [50000,256]
  const int* spans   = (const int*)d_in[4];    // [16,128,2]
  const int* labels  = (const int*)d_in[5];    // [16,2,128]
  float* out = (float*)d_out;                  // [1 + 16*128*256]
  float* ws = (float*)d_ws;

  // workspace layout (floats)
  float* W      = ws;                         // [16][256][768]  sampled in-chunk cumsums
  float* P      = W + (size_t)BSZ * NSPAN * HID;   // [16][64][768] chunk sums -> exclusive prefix
  float* MV     = P + (size_t)BSZ * NCH * HID;     // [2048][768]  mention vectors
  float* WT     = MV + (size_t)NTOT * HID;         // [768][256]   linear_w transposed
  float* EVa    = WT + (size_t)HID * ENT;          // [2048][256]  aligned entity vectors
  float* LET    = EVa + (size_t)NTOT * ENT;        // [256][2048]  label embs transposed
  float* perrow = LET + (size_t)ENT * NTOT;        // [2048]

  span_scan_kernel<<<BSZ * NCH, 192, 0, stream>>>(seq, spans, W, P);
  chunk_prefix_kernel<<<(BSZ * H4 + 255) / 256, 256, 0, stream>>>(P);
  mention_vec_kernel<<<(NTOT * H4 + 255) / 256, 256, 0, stream>>>(W, P, spans, MV);
  wt_transpose_kernel<<<(ENT * HID + 255) / 256, 256, 0, stream>>>(lw, WT);
  ev_gemm_kernel<<<NTOT / EVROWS, 256, 0, stream>>>(MV, WT, lb, EVa, out);
  gather_le_kernel<<<NTOT, 64, 0, stream>>>(table, labels, LET);
  loss_rows_kernel<<<NTOT / LROWS, 256, 0, stream>>>(EVa, LET, perrow);
  finalize_kernel<<<1, 256, 0, stream>>>(perrow, labels, out);
}